// Round 9
// baseline (292.269 us; speedup 1.0000x reference)
//
#include <hip/hip_runtime.h>
#include <hip/hip_bf16.h>

// Problem: B=64, K=512 (KPLUS1=513), D=E=1024
// out[b,k] = softmax_k( sum_e tanh( (z[b,k,:]@Wz)[e] + (u[b,:]@Wu)[e] ) * bias[e] )
// R9: traffic-minimal fp16 GEMM. BM=64, BN=1024 (z/x read ONCE), BK=32.
// Fused fp32->fp16 conversion of the A-tile (no prep_z pass). B staged from
// L2-resident wzt via global_load_lds. Swizzle: phys chunk = c ^ ((row>>1)&3)
// on both write and read (2-way max = free). Epilogue: fast tanh, final q.

typedef __attribute__((ext_vector_type(8))) short short8;
typedef __attribute__((ext_vector_type(8))) _Float16 half8;
typedef __attribute__((ext_vector_type(4))) float f32x4;
typedef unsigned short ushort_t;

typedef const __attribute__((address_space(1))) void gvoid_t;
typedef __attribute__((address_space(3))) void lvoid_t;

__device__ __forceinline__ ushort_t f2bf(float f) {
    unsigned u = __float_as_uint(f);
    unsigned r = u + 0x7FFFu + ((u >> 16) & 1u);
    return (ushort_t)(r >> 16);
}
__device__ __forceinline__ float bf2f(ushort_t h) {
    return __uint_as_float(((unsigned)h) << 16);
}
__device__ __forceinline__ float tanh_fast(float x) {
    float e = __expf(2.f * x);
    return 1.f - 2.f / (e + 1.f);
}

// ---------------------------------------------------------------------------
// Kernel 1: transpose Wz ([d][e], rows 0..1023 of dense_weights) -> fp16 [e][d].
__global__ void k_prep_w16(const float* __restrict__ w,
                           _Float16* __restrict__ wzt) {
    __shared__ _Float16 th[64][66];
    const int k0 = blockIdx.x * 64;
    const int n0 = blockIdx.y * 64;
    const int t = threadIdx.x;
    const int lr = t >> 6;
    const int lc = t & 63;
#pragma unroll
    for (int r = 0; r < 16; ++r) {
        int kk = r * 4 + lr;
        th[kk][lc] = (_Float16)w[(size_t)(k0 + kk) * 1024 + n0 + lc];
    }
    __syncthreads();
#pragma unroll
    for (int r = 0; r < 16; ++r) {
        int nn = r * 4 + lr;
        wzt[(size_t)(n0 + nn) * 1024 + k0 + lc] = th[lc][nn];
    }
}

// ---------------------------------------------------------------------------
// Kernel 2: hu[b][e] = sum_d u[b][d] * Wu[d][e], exact fp32.
__global__ void k_hu(const float* __restrict__ x,
                     const float* __restrict__ w,
                     float* __restrict__ hu) {
    __shared__ float us[1024];
    const int b = blockIdx.y;
    const int e = blockIdx.x * 256 + threadIdx.x;
    for (int i = threadIdx.x; i < 1024; i += 256)
        us[i] = x[(size_t)b * 513 * 1024 + i];
    __syncthreads();
    const float* wu = w + (size_t)1024 * 1024;
    float acc = 0.f;
#pragma unroll 8
    for (int d = 0; d < 1024; ++d)
        acc = fmaf(us[d], wu[(size_t)d * 1024 + e], acc);
    hu[b * 1024 + e] = acc;
}

// ---------------------------------------------------------------------------
// Kernel 3: fused-conversion fp16 GEMM. Grid 512 blocks (64-row stripes),
// 256 thr (4 waves, 2M x 2N: wave = 32 rows x 512 cols, acc[2][32]).
// Per K-iter(32): A: 8 f32 loads/thread -> cvt -> 1 ds_write_b128 (swizzled);
// B: 16 global_load_lds/wave from wzt (pre-swizzled source); barrier;
// 2 a-frags + 32 b-frags ds_read; 64 MFMA; barrier.
__global__ __launch_bounds__(256, 2) void k_gemm8(
        const float* __restrict__ x,
        const _Float16* __restrict__ wzt,
        const float* __restrict__ hu,
        const float* __restrict__ bias,
        float* __restrict__ q) {
    __shared__ __align__(16) _Float16 As[64 * 32];     // 4 KiB
    __shared__ __align__(16) _Float16 Bs[1024 * 32];   // 64 KiB
    __shared__ float qred[2][64];

    const int t = threadIdx.x;
    const int mtile = blockIdx.x;   // 0..511
    const int wid = t >> 6;
    const int l = t & 63;
    const int wm = wid >> 1;        // 0..1 -> rows wm*32
    const int wn = wid & 1;         // 0..1 -> cols wn*512
    const int lr = l & 15;
    const int g = l >> 4;           // logical k-chunk 0..3

    // ---- A staging: thread -> row r=t>>2 (0..63), logical chunk cl=t&3 ----
    const int r = t >> 2;
    const int cl = t & 3;
    const int bb = mtile >> 3;                 // batch (block-uniform)
    const int kk = (mtile & 7) * 64 + r;       // k-row within batch
    const float* xrow = x + (((size_t)(bb * 513 + 1 + kk)) << 10) + cl * 8;
    _Float16* awr = As + r * 32 + ((cl ^ ((r >> 1) & 3)) * 8);

    // ---- B staging: wave wid does 16 x 1KiB gload_lds; call j:
    // e = wid*256 + j*16 + (l>>2); phys chunk l&3; src chunk (l&3)^((l>>3)&3).
    const int sck = ((l & 3) ^ ((l >> 3) & 3)) * 8;
    const _Float16* bsrc = wzt + (size_t)(wid * 256 + (l >> 2)) * 1024 + sck;
    char* bdst = (char*)Bs + (wid * 16) * 1024 + l * 16;

    f32x4 acc[2][32] = {};
    const int swz = (g ^ ((lr >> 1) & 3)) * 16;   // ds_read byte slot

    for (int k0 = 0; k0 < 1024; k0 += 32) {
        // A: load 8 fp32, convert, one swizzled ds_write_b128
        const float4 v0 = *(const float4*)(xrow + k0);
        const float4 v1 = *(const float4*)(xrow + k0 + 4);
        half8 hv;
        hv[0] = (_Float16)v0.x; hv[1] = (_Float16)v0.y;
        hv[2] = (_Float16)v0.z; hv[3] = (_Float16)v0.w;
        hv[4] = (_Float16)v1.x; hv[5] = (_Float16)v1.y;
        hv[6] = (_Float16)v1.z; hv[7] = (_Float16)v1.w;
        *(half8*)awr = hv;
        // B: 16 direct global->LDS loads
#pragma unroll
        for (int j = 0; j < 16; ++j) {
            __builtin_amdgcn_global_load_lds(
                (gvoid_t*)(bsrc + (size_t)j * 16 * 1024 + k0),
                (lvoid_t*)(bdst + j * 1024), 16, 0, 0);
        }
        __syncthreads();

        half8 afr[2];
#pragma unroll
        for (int mi = 0; mi < 2; ++mi)
            afr[mi] = *(const half8*)((const char*)As + (wm * 32 + mi * 16 + lr) * 64 + swz);
#pragma unroll
        for (int ni = 0; ni < 32; ++ni) {
            const half8 bfr = *(const half8*)((const char*)Bs + (wn * 512 + ni * 16 + lr) * 64 + swz);
            acc[0][ni] = __builtin_amdgcn_mfma_f32_16x16x32_f16(afr[0], bfr, acc[0][ni], 0, 0, 0);
            acc[1][ni] = __builtin_amdgcn_mfma_f32_16x16x32_f16(afr[1], bfr, acc[1][ni], 0, 0, 0);
        }
        __syncthreads();
    }

    // ---- epilogue: q[row] = sum_e tanh(s + hu)*bias, all 1024 e in-block ----
    const float* hup = hu + bb * 1024 + wn * 512 + lr;
    const float* bip = bias + wn * 512 + lr;
    float v[2][4] = {};
#pragma unroll
    for (int ni = 0; ni < 32; ++ni) {
        const float hue = hup[ni * 16];
        const float bie = bip[ni * 16];
#pragma unroll
        for (int mi = 0; mi < 2; ++mi)
#pragma unroll
            for (int j = 0; j < 4; ++j)
                v[mi][j] += tanh_fast(acc[mi][ni][j] + hue) * bie;
    }
#pragma unroll
    for (int mi = 0; mi < 2; ++mi)
#pragma unroll
        for (int j = 0; j < 4; ++j) {
            float vv = v[mi][j];
            vv += __shfl_xor(vv, 1);
            vv += __shfl_xor(vv, 2);
            vv += __shfl_xor(vv, 4);
            vv += __shfl_xor(vv, 8);
            if (lr == 0)
                qred[wn][wm * 32 + mi * 16 + g * 4 + j] = vv;
        }
    __syncthreads();
    if (t < 64)
        q[mtile * 64 + t] = qred[0][t] + qred[1][t];
}

// ---------------------------------------------------------------------------
// Fallback path (R2-verified): split-bf16, in-loop staging (ws too small).
__global__ void k_prep_w(const float* __restrict__ w,
                         ushort_t* __restrict__ wzt_hi,
                         ushort_t* __restrict__ wzt_lo) {
    __shared__ ushort_t th[64][66];
    __shared__ ushort_t tl[64][66];
    const int k0 = blockIdx.x * 64;
    const int n0 = blockIdx.y * 64;
    const int t = threadIdx.x;
    const int lr = t >> 6;
    const int lc = t & 63;
#pragma unroll
    for (int r = 0; r < 16; ++r) {
        int kk = r * 4 + lr;
        float f = w[(size_t)(k0 + kk) * 1024 + n0 + lc];
        ushort_t hi = f2bf(f);
        ushort_t lo = f2bf(f - bf2f(hi));
        th[kk][lc] = hi;
        tl[kk][lc] = lo;
    }
    __syncthreads();
#pragma unroll
    for (int r = 0; r < 16; ++r) {
        int nn = r * 4 + lr;
        wzt_hi[(size_t)(n0 + nn) * 1024 + k0 + lc] = th[lc][nn];
        wzt_lo[(size_t)(n0 + nn) * 1024 + k0 + lc] = tl[lc][nn];
    }
}

__global__ __launch_bounds__(256) void k_gemm(
        const float* __restrict__ x,
        const ushort_t* __restrict__ wzt_hi,
        const ushort_t* __restrict__ wzt_lo,
        const float* __restrict__ hu,
        const float* __restrict__ bias,
        float* __restrict__ qp) {
    __shared__ ushort_t As_hi[128][40];
    __shared__ ushort_t As_lo[128][40];
    __shared__ ushort_t Bs_hi[128][40];
    __shared__ ushort_t Bs_lo[128][40];
    __shared__ float qred[2][2][64];

    const int t = threadIdx.x;
    const int mtile = blockIdx.x;
    const int ntile = blockIdx.y;
    const int wid = t >> 6;
    const int l = t & 63;
    const int wm = wid >> 1;
    const int wn = wid & 1;

    f32x4 acc[4][4] = {};

    const int arow = t >> 3;
    const int acol = (t & 7) * 4;
    size_t abase[4];
#pragma unroll
    for (int it = 0; it < 4; ++it) {
        int m = mtile * 128 + arow + it * 32;
        int bb = m >> 9;
        int kk = m & 511;
        abase[it] = ((size_t)(bb * 513 + 1 + kk)) * 1024 + acol;
    }
    const int brow = t >> 2;
    const int bcol = (t & 3) * 8;
    const size_t bbase = (size_t)(ntile * 128 + brow) * 1024 + bcol;

    for (int k0 = 0; k0 < 1024; k0 += 32) {
#pragma unroll
        for (int it = 0; it < 4; ++it) {
            const float4 v = *(const float4*)(x + abase[it] + k0);
            ushort4 hv, lv;
            hv.x = f2bf(v.x); lv.x = f2bf(v.x - bf2f(hv.x));
            hv.y = f2bf(v.y); lv.y = f2bf(v.y - bf2f(hv.y));
            hv.z = f2bf(v.z); lv.z = f2bf(v.z - bf2f(hv.z));
            hv.w = f2bf(v.w); lv.w = f2bf(v.w - bf2f(hv.w));
            const int row = arow + it * 32;
            *(ushort4*)&As_hi[row][acol] = hv;
            *(ushort4*)&As_lo[row][acol] = lv;
        }
#pragma unroll
        for (int it = 0; it < 2; ++it) {
            const int row = brow + it * 64;
            const uint4 vh = *(const uint4*)(wzt_hi + bbase + (size_t)it * 64 * 1024 + k0);
            const uint4 vl = *(const uint4*)(wzt_lo + bbase + (size_t)it * 64 * 1024 + k0);
            *(uint4*)&Bs_hi[row][bcol] = vh;
            *(uint4*)&Bs_lo[row][bcol] = vl;
        }
        __syncthreads();

        const int lr = l & 15;
        const int lk = (l >> 4) * 8;
        short8 ah[4], al[4], bh[4], bl[4];
#pragma unroll
        for (int i = 0; i < 4; ++i) {
            ah[i] = *(const short8*)&As_hi[wm * 64 + i * 16 + lr][lk];
            al[i] = *(const short8*)&As_lo[wm * 64 + i * 16 + lr][lk];
            bh[i] = *(const short8*)&Bs_hi[wn * 64 + i * 16 + lr][lk];
            bl[i] = *(const short8*)&Bs_lo[wn * 64 + i * 16 + lr][lk];
        }
#pragma unroll
        for (int mi = 0; mi < 4; ++mi)
#pragma unroll
            for (int ni = 0; ni < 4; ++ni) {
                acc[mi][ni] = __builtin_amdgcn_mfma_f32_16x16x32_bf16(ah[mi], bh[ni], acc[mi][ni], 0, 0, 0);
                acc[mi][ni] = __builtin_amdgcn_mfma_f32_16x16x32_bf16(ah[mi], bl[ni], acc[mi][ni], 0, 0, 0);
                acc[mi][ni] = __builtin_amdgcn_mfma_f32_16x16x32_bf16(al[mi], bh[ni], acc[mi][ni], 0, 0, 0);
            }
        __syncthreads();
    }

    const int lr = l & 15;
    const int lg = l >> 4;
    const int bbatch = mtile >> 2;
    float hu4[4], bias4[4];
#pragma unroll
    for (int ni = 0; ni < 4; ++ni) {
        int e = ntile * 128 + wn * 64 + ni * 16 + lr;
        hu4[ni] = hu[bbatch * 1024 + e];
        bias4[ni] = bias[e];
    }
#pragma unroll
    for (int mi = 0; mi < 4; ++mi) {
#pragma unroll
        for (int j = 0; j < 4; ++j) {
            float v = 0.f;
#pragma unroll
            for (int ni = 0; ni < 4; ++ni)
                v += tanhf(acc[mi][ni][j] + hu4[ni]) * bias4[ni];
            v += __shfl_xor(v, 1);
            v += __shfl_xor(v, 2);
            v += __shfl_xor(v, 4);
            v += __shfl_xor(v, 8);
            if (lr == 0)
                qred[wm][wn][mi * 16 + lg * 4 + j] = v;
        }
    }
    __syncthreads();
    if (t < 128) {
        const int wmr = t >> 6;
        const int rr = t & 63;
        float qv = qred[wmr][0][rr] + qred[wmr][1][rr];
        qp[(size_t)ntile * 32768 + mtile * 128 + t] = qv;
    }
}

// ---------------------------------------------------------------------------
// Kernel 4: reduce partials over nt tiles + softmax over k (512) per batch.
__global__ void k_softmax(const float* __restrict__ qp, float* __restrict__ out,
                          int nt) {
    const int b = blockIdx.x;
    const int k = threadIdx.x;   // 512 threads
    float q = 0.f;
    for (int i = 0; i < nt; ++i)
        q += qp[(size_t)i * 32768 + b * 512 + k];

    __shared__ float redm[8];
    __shared__ float reds[8];
    const int wid = k >> 6;

    float m = q;
#pragma unroll
    for (int off = 32; off >= 1; off >>= 1)
        m = fmaxf(m, __shfl_xor(m, off));
    if ((k & 63) == 0) redm[wid] = m;
    __syncthreads();
    m = redm[0];
#pragma unroll
    for (int i = 1; i < 8; ++i) m = fmaxf(m, redm[i]);

    float p = expf(q - m);
    float s = p;
#pragma unroll
    for (int off = 32; off >= 1; off >>= 1)
        s += __shfl_xor(s, off);
    if ((k & 63) == 0) reds[wid] = s;
    __syncthreads();
    s = 0.f;
#pragma unroll
    for (int i = 0; i < 8; ++i) s += reds[i];

    out[b * 512 + k] = p / s;
}

// ---------------------------------------------------------------------------
extern "C" void kernel_launch(void* const* d_in, const int* in_sizes, int n_in,
                              void* d_out, int out_size, void* d_ws, size_t ws_size,
                              hipStream_t stream) {
    const float* x    = (const float*)d_in[0];   // (64, 513, 1024) f32
    const float* w    = (const float*)d_in[1];   // (2048, 1024) f32
    const float* bias = (const float*)d_in[2];   // (1024, 1) f32
    float* out = (float*)d_out;                  // (64, 512) f32

    char* ws = (char*)d_ws;

    // fast-path ws: wzt (2MB fp16) + hu (256KB) + q (128KB)
    const size_t need = (size_t)1024 * 1024 * sizeof(_Float16)
                      + (size_t)64 * 1024 * sizeof(float)
                      + (size_t)32768 * sizeof(float);

    if (ws_size >= need) {
        _Float16* wzt = (_Float16*)ws;
        float*    hu  = (float*)(wzt + (size_t)1024 * 1024);
        float*    q   = hu + (size_t)64 * 1024;

        k_prep_w16<<<dim3(16, 16), 256, 0, stream>>>(w, wzt);
        k_hu<<<dim3(4, 64), 256, 0, stream>>>(x, w, hu);
        k_gemm8<<<512, 256, 0, stream>>>(x, wzt, hu, bias, q);
        k_softmax<<<64, 512, 0, stream>>>(q, out, 1);
    } else {
        ushort_t* wzt_hi = (ushort_t*)ws;
        ushort_t* wzt_lo = wzt_hi + (size_t)1024 * 1024;
        float* hu = (float*)(ws + (size_t)4 * 1024 * 1024);
        float* qp = hu + (size_t)64 * 1024;

        k_prep_w<<<dim3(16, 16), 256, 0, stream>>>(w, wzt_hi, wzt_lo);
        k_hu<<<dim3(4, 64), 256, 0, stream>>>(x, w, hu);
        k_gemm<<<dim3(256, 8), 256, 0, stream>>>(x, wzt_hi, wzt_lo, hu, bias, qp);
        k_softmax<<<64, 512, 0, stream>>>(qp, out, 8);
    }
}

// Round 10
// 180.585 us; speedup vs baseline: 1.6185x; 1.6185x over previous
//
#include <hip/hip_runtime.h>
#include <hip/hip_bf16.h>

// Problem: B=64, K=512 (KPLUS1=513), D=E=1024
// out[b,k] = softmax_k( sum_e tanh( (z[b,k,:]@Wz)[e] + (u[b,:]@Wu)[e] ) * bias[e] )
// R10: fp16 single-product GEMM, BM=BN=256 to halve staged bytes (the
// measured limiter). 512 thr / 8 waves (2Mx4N), wave=128x64, acc[8][4]
// (=128 VGPR, no spill). R3-proven gload_lds staging + XOR swizzle.

typedef __attribute__((ext_vector_type(8))) short short8;
typedef __attribute__((ext_vector_type(8))) _Float16 half8;
typedef __attribute__((ext_vector_type(4))) float f32x4;
typedef unsigned short ushort_t;

typedef const __attribute__((address_space(1))) void gvoid_t;
typedef __attribute__((address_space(3))) void lvoid_t;

__device__ __forceinline__ ushort_t f2bf(float f) {
    unsigned u = __float_as_uint(f);
    unsigned r = u + 0x7FFFu + ((u >> 16) & 1u);
    return (ushort_t)(r >> 16);
}
__device__ __forceinline__ float bf2f(ushort_t h) {
    return __uint_as_float(((unsigned)h) << 16);
}
__device__ __forceinline__ float tanh_fast(float x) {
    float e = __expf(2.f * x);
    return 1.f - 2.f / (e + 1.f);
}

// ---------------------------------------------------------------------------
// Kernel 0 (fast path): convert z = x[:,1:,:] to fp16 [32768][1024].
__global__ __launch_bounds__(256) void k_prep_z16(const float* __restrict__ x,
                                                  _Float16* __restrict__ z_h) {
    const int idx8 = blockIdx.x * 256 + threadIdx.x;
    const int m = idx8 >> 7;
    const int c = (idx8 & 127) * 8;
    const int b = m >> 9, k = m & 511;
    const float* src = x + ((size_t)(b * 513 + 1 + k) << 10) + c;
    const float4 v0 = *(const float4*)src;
    const float4 v1 = *(const float4*)(src + 4);
    float vv[8] = {v0.x, v0.y, v0.z, v0.w, v1.x, v1.y, v1.z, v1.w};
    half8 hv;
#pragma unroll
    for (int i = 0; i < 8; ++i) hv[i] = (_Float16)vv[i];
    *(half8*)(z_h + (size_t)m * 1024 + c) = hv;
}

// ---------------------------------------------------------------------------
// Kernel 1 (fast path): transpose Wz ([d][e], rows 0..1023) -> fp16 wzt [e][d].
__global__ void k_prep_w16(const float* __restrict__ w,
                           _Float16* __restrict__ wzt) {
    __shared__ _Float16 th[64][66];
    const int k0 = blockIdx.x * 64;
    const int n0 = blockIdx.y * 64;
    const int t = threadIdx.x;
    const int lr = t >> 6;
    const int lc = t & 63;
#pragma unroll
    for (int r = 0; r < 16; ++r) {
        int kk = r * 4 + lr;
        th[kk][lc] = (_Float16)w[(size_t)(k0 + kk) * 1024 + n0 + lc];
    }
    __syncthreads();
#pragma unroll
    for (int r = 0; r < 16; ++r) {
        int nn = r * 4 + lr;
        wzt[(size_t)(n0 + nn) * 1024 + k0 + lc] = th[lc][nn];
    }
}

// ---------------------------------------------------------------------------
// Kernel 2: hu[b][e] = sum_d u[b][d] * Wu[d][e], exact fp32.
__global__ void k_hu(const float* __restrict__ x,
                     const float* __restrict__ w,
                     float* __restrict__ hu) {
    __shared__ float us[1024];
    const int b = blockIdx.y;
    const int e = blockIdx.x * 256 + threadIdx.x;
    for (int i = threadIdx.x; i < 1024; i += 256)
        us[i] = x[(size_t)b * 513 * 1024 + i];
    __syncthreads();
    const float* wu = w + (size_t)1024 * 1024;
    float acc = 0.f;
#pragma unroll 8
    for (int d = 0; d < 1024; ++d)
        acc = fmaf(us[d], wu[(size_t)d * 1024 + e], acc);
    hu[b * 1024 + e] = acc;
}

// ---------------------------------------------------------------------------
// Kernel 3 (fast path): fp16 GEMM, BM=BN=256, BK=64. 8 waves 2Mx4N,
// wave = 128x64 (8x4 frags of 16x16x32). Waves 0-3 stage A (32KB),
// waves 4-7 stage B (32KB) via global_load_lds(16B), pre-swizzled source
// chunk=(l&7)^rl, linear LDS; ds_read XOR (ks*4+g)^(lr&7). 2 barriers/iter.
__global__ __launch_bounds__(512, 2) void k_gemm9(
        const _Float16* __restrict__ z_h,
        const _Float16* __restrict__ wzt,
        const float* __restrict__ hu,
        const float* __restrict__ bias,
        float* __restrict__ qp) {
    __shared__ __align__(16) _Float16 As[256 * 64];   // 32 KiB
    __shared__ __align__(16) _Float16 Bs[256 * 64];   // 32 KiB
    __shared__ float qred[2][4][128];                 // 4 KiB

    const int t = threadIdx.x;          // 0..511
    const int mtile = blockIdx.x;       // 0..127 (256 rows)
    const int ntile = blockIdx.y;       // 0..3   (256 cols)
    const int wid = t >> 6;
    const int l = t & 63;
    const int wm = wid >> 2;            // 0..1 -> rows wm*128
    const int wn = wid & 3;             // 0..3 -> cols wn*64
    const int lr = l & 15;
    const int g = l >> 4;               // 0..3

    // ---- staging: waves 0-3 -> A rows w4*64..+64; waves 4-7 -> B same.
    // call j: row = w4*64 + j*8 + rl; phys slot (l&7); src chunk (l&7)^rl.
    const int rl = l >> 3;
    const int chunk = (l & 7) ^ rl;
    const int w4 = wid & 3;
    const _Float16* gsrc;
    _Float16* ldsT;
    if (wid < 4) {
        gsrc = z_h + (size_t)(mtile * 256 + w4 * 64 + rl) * 1024 + chunk * 8;
        ldsT = As + w4 * 4096;
    } else {
        gsrc = wzt + (size_t)(ntile * 256 + w4 * 64 + rl) * 1024 + chunk * 8;
        ldsT = Bs + w4 * 4096;
    }

    f32x4 acc[8][4] = {};

    for (int k0 = 0; k0 < 1024; k0 += 64) {
        // ---- stage 64KB via direct global->LDS DMA (8 calls/thread) ----
#pragma unroll
        for (int j = 0; j < 8; ++j) {
            __builtin_amdgcn_global_load_lds(
                (gvoid_t*)(gsrc + k0 + j * 8192),
                (lvoid_t*)((char*)ldsT + j * 1024 + l * 16),
                16, 0, 0);
        }
        __syncthreads();   // compiler drains vmcnt before barrier

        // ---- compute: 2 k-subtiles of 32, 32 MFMA each ----
#pragma unroll
        for (int ks = 0; ks < 2; ++ks) {
            half8 afr[8], bfr[4];
            const int so = ((ks * 4 + g) ^ (lr & 7)) * 16;
#pragma unroll
            for (int ni = 0; ni < 4; ++ni)
                bfr[ni] = *(const half8*)((const char*)Bs + (wn * 64 + ni * 16 + lr) * 128 + so);
#pragma unroll
            for (int mi = 0; mi < 8; ++mi)
                afr[mi] = *(const half8*)((const char*)As + (wm * 128 + mi * 16 + lr) * 128 + so);
#pragma unroll
            for (int mi = 0; mi < 8; ++mi)
#pragma unroll
                for (int ni = 0; ni < 4; ++ni)
                    acc[mi][ni] = __builtin_amdgcn_mfma_f32_16x16x32_f16(
                        afr[mi], bfr[ni], acc[mi][ni], 0, 0, 0);
        }
        __syncthreads();
    }

    // ---- epilogue: partial q over this wave's 64 e-cols ----
    const int bb = mtile >> 1;      // 256 | 512 -> batch block-uniform
    float hu4[4], bias4[4];
#pragma unroll
    for (int ni = 0; ni < 4; ++ni) {
        int e = ntile * 256 + wn * 64 + ni * 16 + lr;
        hu4[ni] = hu[bb * 1024 + e];
        bias4[ni] = bias[e];
    }
#pragma unroll
    for (int mi = 0; mi < 8; ++mi) {
#pragma unroll
        for (int j = 0; j < 4; ++j) {
            float v = 0.f;
#pragma unroll
            for (int ni = 0; ni < 4; ++ni)
                v += tanh_fast(acc[mi][ni][j] + hu4[ni]) * bias4[ni];
            v += __shfl_xor(v, 1);
            v += __shfl_xor(v, 2);
            v += __shfl_xor(v, 4);
            v += __shfl_xor(v, 8);
            if (lr == 0)
                qred[wm][wn][mi * 16 + g * 4 + j] = v;
        }
    }
    __syncthreads();
    if (t < 256) {
        const int wmr = t >> 7;
        const int rr = t & 127;
        float q = qred[wmr][0][rr] + qred[wmr][1][rr]
                + qred[wmr][2][rr] + qred[wmr][3][rr];
        qp[(size_t)ntile * 32768 + mtile * 256 + t] = q;
    }
}

// ---------------------------------------------------------------------------
// Fallback path (R2-verified): split-bf16, in-loop staging (ws too small).
__global__ void k_prep_w(const float* __restrict__ w,
                         ushort_t* __restrict__ wzt_hi,
                         ushort_t* __restrict__ wzt_lo) {
    __shared__ ushort_t th[64][66];
    __shared__ ushort_t tl[64][66];
    const int k0 = blockIdx.x * 64;
    const int n0 = blockIdx.y * 64;
    const int t = threadIdx.x;
    const int lr = t >> 6;
    const int lc = t & 63;
#pragma unroll
    for (int r = 0; r < 16; ++r) {
        int kk = r * 4 + lr;
        float f = w[(size_t)(k0 + kk) * 1024 + n0 + lc];
        ushort_t hi = f2bf(f);
        ushort_t lo = f2bf(f - bf2f(hi));
        th[kk][lc] = hi;
        tl[kk][lc] = lo;
    }
    __syncthreads();
#pragma unroll
    for (int r = 0; r < 16; ++r) {
        int nn = r * 4 + lr;
        wzt_hi[(size_t)(n0 + nn) * 1024 + k0 + lc] = th[lc][nn];
        wzt_lo[(size_t)(n0 + nn) * 1024 + k0 + lc] = tl[lc][nn];
    }
}

__global__ __launch_bounds__(256) void k_gemm(
        const float* __restrict__ x,
        const ushort_t* __restrict__ wzt_hi,
        const ushort_t* __restrict__ wzt_lo,
        const float* __restrict__ hu,
        const float* __restrict__ bias,
        float* __restrict__ qp) {
    __shared__ ushort_t As_hi[128][40];
    __shared__ ushort_t As_lo[128][40];
    __shared__ ushort_t Bs_hi[128][40];
    __shared__ ushort_t Bs_lo[128][40];
    __shared__ float qred[2][2][64];

    const int t = threadIdx.x;
    const int mtile = blockIdx.x;
    const int ntile = blockIdx.y;
    const int wid = t >> 6;
    const int l = t & 63;
    const int wm = wid >> 1;
    const int wn = wid & 1;

    f32x4 acc[4][4] = {};

    const int arow = t >> 3;
    const int acol = (t & 7) * 4;
    size_t abase[4];
#pragma unroll
    for (int it = 0; it < 4; ++it) {
        int m = mtile * 128 + arow + it * 32;
        int bb = m >> 9;
        int kk = m & 511;
        abase[it] = ((size_t)(bb * 513 + 1 + kk)) * 1024 + acol;
    }
    const int brow = t >> 2;
    const int bcol = (t & 3) * 8;
    const size_t bbase = (size_t)(ntile * 128 + brow) * 1024 + bcol;

    for (int k0 = 0; k0 < 1024; k0 += 32) {
#pragma unroll
        for (int it = 0; it < 4; ++it) {
            const float4 v = *(const float4*)(x + abase[it] + k0);
            ushort4 hv, lv;
            hv.x = f2bf(v.x); lv.x = f2bf(v.x - bf2f(hv.x));
            hv.y = f2bf(v.y); lv.y = f2bf(v.y - bf2f(hv.y));
            hv.z = f2bf(v.z); lv.z = f2bf(v.z - bf2f(hv.z));
            hv.w = f2bf(v.w); lv.w = f2bf(v.w - bf2f(hv.w));
            const int row = arow + it * 32;
            *(ushort4*)&As_hi[row][acol] = hv;
            *(ushort4*)&As_lo[row][acol] = lv;
        }
#pragma unroll
        for (int it = 0; it < 2; ++it) {
            const int row = brow + it * 64;
            const uint4 vh = *(const uint4*)(wzt_hi + bbase + (size_t)it * 64 * 1024 + k0);
            const uint4 vl = *(const uint4*)(wzt_lo + bbase + (size_t)it * 64 * 1024 + k0);
            *(uint4*)&Bs_hi[row][bcol] = vh;
            *(uint4*)&Bs_lo[row][bcol] = vl;
        }
        __syncthreads();

        const int lr = l & 15;
        const int lk = (l >> 4) * 8;
        short8 ah[4], al[4], bh[4], bl[4];
#pragma unroll
        for (int i = 0; i < 4; ++i) {
            ah[i] = *(const short8*)&As_hi[wm * 64 + i * 16 + lr][lk];
            al[i] = *(const short8*)&As_lo[wm * 64 + i * 16 + lr][lk];
            bh[i] = *(const short8*)&Bs_hi[wn * 64 + i * 16 + lr][lk];
            bl[i] = *(const short8*)&Bs_lo[wn * 64 + i * 16 + lr][lk];
        }
#pragma unroll
        for (int mi = 0; mi < 4; ++mi)
#pragma unroll
            for (int ni = 0; ni < 4; ++ni) {
                acc[mi][ni] = __builtin_amdgcn_mfma_f32_16x16x32_bf16(ah[mi], bh[ni], acc[mi][ni], 0, 0, 0);
                acc[mi][ni] = __builtin_amdgcn_mfma_f32_16x16x32_bf16(ah[mi], bl[ni], acc[mi][ni], 0, 0, 0);
                acc[mi][ni] = __builtin_amdgcn_mfma_f32_16x16x32_bf16(al[mi], bh[ni], acc[mi][ni], 0, 0, 0);
            }
        __syncthreads();
    }

    const int lr = l & 15;
    const int lg = l >> 4;
    const int bbatch = mtile >> 2;
    float hu4[4], bias4[4];
#pragma unroll
    for (int ni = 0; ni < 4; ++ni) {
        int e = ntile * 128 + wn * 64 + ni * 16 + lr;
        hu4[ni] = hu[bbatch * 1024 + e];
        bias4[ni] = bias[e];
    }
#pragma unroll
    for (int mi = 0; mi < 4; ++mi) {
#pragma unroll
        for (int j = 0; j < 4; ++j) {
            float v = 0.f;
#pragma unroll
            for (int ni = 0; ni < 4; ++ni)
                v += tanhf(acc[mi][ni][j] + hu4[ni]) * bias4[ni];
            v += __shfl_xor(v, 1);
            v += __shfl_xor(v, 2);
            v += __shfl_xor(v, 4);
            v += __shfl_xor(v, 8);
            if (lr == 0)
                qred[wm][wn][mi * 16 + lg * 4 + j] = v;
        }
    }
    __syncthreads();
    if (t < 128) {
        const int wmr = t >> 6;
        const int rr = t & 63;
        float qv = qred[wmr][0][rr] + qred[wmr][1][rr];
        qp[(size_t)ntile * 32768 + mtile * 128 + t] = qv;
    }
}

// ---------------------------------------------------------------------------
// Kernel 4: reduce partials over nt tiles + softmax over k (512) per batch.
__global__ void k_softmax(const float* __restrict__ qp, float* __restrict__ out,
                          int nt) {
    const int b = blockIdx.x;
    const int k = threadIdx.x;   // 512 threads
    float q = 0.f;
    for (int i = 0; i < nt; ++i)
        q += qp[(size_t)i * 32768 + b * 512 + k];

    __shared__ float redm[8];
    __shared__ float reds[8];
    const int wid = k >> 6;

    float m = q;
#pragma unroll
    for (int off = 32; off >= 1; off >>= 1)
        m = fmaxf(m, __shfl_xor(m, off));
    if ((k & 63) == 0) redm[wid] = m;
    __syncthreads();
    m = redm[0];
#pragma unroll
    for (int i = 1; i < 8; ++i) m = fmaxf(m, redm[i]);

    float p = expf(q - m);
    float s = p;
#pragma unroll
    for (int off = 32; off >= 1; off >>= 1)
        s += __shfl_xor(s, off);
    if ((k & 63) == 0) reds[wid] = s;
    __syncthreads();
    s = 0.f;
#pragma unroll
    for (int i = 0; i < 8; ++i) s += reds[i];

    out[b * 512 + k] = p / s;
}

// ---------------------------------------------------------------------------
extern "C" void kernel_launch(void* const* d_in, const int* in_sizes, int n_in,
                              void* d_out, int out_size, void* d_ws, size_t ws_size,
                              hipStream_t stream) {
    const float* x    = (const float*)d_in[0];   // (64, 513, 1024) f32
    const float* w    = (const float*)d_in[1];   // (2048, 1024) f32
    const float* bias = (const float*)d_in[2];   // (1024, 1) f32
    float* out = (float*)d_out;                  // (64, 512) f32

    char* ws = (char*)d_ws;
    const size_t ZN = (size_t)32768 * 1024;      // z elements

    // fast-path ws: z_h (64MB fp16) + wzt (2MB fp16) + hu (256KB) + qp (512KB)
    const size_t need = ZN * sizeof(_Float16)
                      + (size_t)1024 * 1024 * sizeof(_Float16)
                      + (size_t)64 * 1024 * sizeof(float)
                      + (size_t)4 * 32768 * sizeof(float);

    if (ws_size >= need) {
        _Float16* z_h = (_Float16*)ws;
        _Float16* wzt = z_h + ZN;
        float*    hu  = (float*)(wzt + (size_t)1024 * 1024);
        float*    qp  = hu + (size_t)64 * 1024;

        k_prep_z16<<<16384, 256, 0, stream>>>(x, z_h);
        k_prep_w16<<<dim3(16, 16), 256, 0, stream>>>(w, wzt);
        k_hu<<<dim3(4, 64), 256, 0, stream>>>(x, w, hu);
        k_gemm9<<<dim3(128, 4), 512, 0, stream>>>(z_h, wzt, hu, bias, qp);
        k_softmax<<<64, 512, 0, stream>>>(qp, out, 4);
    } else {
        ushort_t* wzt_hi = (ushort_t*)ws;
        ushort_t* wzt_lo = wzt_hi + (size_t)1024 * 1024;
        float* hu = (float*)(ws + (size_t)4 * 1024 * 1024);
        float* qp = hu + (size_t)64 * 1024;

        k_prep_w<<<dim3(16, 16), 256, 0, stream>>>(w, wzt_hi, wzt_lo);
        k_hu<<<dim3(4, 64), 256, 0, stream>>>(x, w, hu);
        k_gemm<<<dim3(256, 8), 256, 0, stream>>>(x, wzt_hi, wzt_lo, hu, bias, qp);
        k_softmax<<<64, 512, 0, stream>>>(qp, out, 8);
    }
}

// Round 11
// 174.151 us; speedup vs baseline: 1.6782x; 1.0369x over previous
//
#include <hip/hip_runtime.h>
#include <hip/hip_bf16.h>

// Problem: B=64, K=512 (KPLUS1=513), D=E=1024
// out[b,k] = softmax_k( sum_e tanh( (z[b,k,:]@Wz)[e] + (u[b,:]@Wu)[e] ) * bias[e] )
// R11: fp16 single-product GEMM, BM=BN=256, with the fp32->fp16 conversion
// of A FUSED into the GEMM (kills the prep_z pass: -94MB HBM, -30us).
// A: reg-stage 8xfloat4 from x, cvt, 4x swizzled ds_write_b128 (R9-proven
// pattern). B: global_load_lds(16B) w/ pre-swizzled source (R10-proven).
// acc[8][4]=128 VGPR (no spill). 2-barrier loop, 0 bank conflicts.

typedef __attribute__((ext_vector_type(8))) short short8;
typedef __attribute__((ext_vector_type(8))) _Float16 half8;
typedef __attribute__((ext_vector_type(4))) float f32x4;
typedef unsigned short ushort_t;

typedef const __attribute__((address_space(1))) void gvoid_t;
typedef __attribute__((address_space(3))) void lvoid_t;

__device__ __forceinline__ ushort_t f2bf(float f) {
    unsigned u = __float_as_uint(f);
    unsigned r = u + 0x7FFFu + ((u >> 16) & 1u);
    return (ushort_t)(r >> 16);
}
__device__ __forceinline__ float bf2f(ushort_t h) {
    return __uint_as_float(((unsigned)h) << 16);
}
__device__ __forceinline__ float tanh_fast(float x) {
    float e = __expf(2.f * x);
    return 1.f - 2.f / (e + 1.f);
}

// ---------------------------------------------------------------------------
// Kernel 1: transpose Wz ([d][e], rows 0..1023 of dense_weights) -> fp16 [e][d].
__global__ void k_prep_w16(const float* __restrict__ w,
                           _Float16* __restrict__ wzt) {
    __shared__ _Float16 th[64][66];
    const int k0 = blockIdx.x * 64;
    const int n0 = blockIdx.y * 64;
    const int t = threadIdx.x;
    const int lr = t >> 6;
    const int lc = t & 63;
#pragma unroll
    for (int r = 0; r < 16; ++r) {
        int kk = r * 4 + lr;
        th[kk][lc] = (_Float16)w[(size_t)(k0 + kk) * 1024 + n0 + lc];
    }
    __syncthreads();
#pragma unroll
    for (int r = 0; r < 16; ++r) {
        int nn = r * 4 + lr;
        wzt[(size_t)(n0 + nn) * 1024 + k0 + lc] = th[lc][nn];
    }
}

// ---------------------------------------------------------------------------
// Kernel 2: hu[b][e] = sum_d u[b][d] * Wu[d][e], exact fp32.
__global__ void k_hu(const float* __restrict__ x,
                     const float* __restrict__ w,
                     float* __restrict__ hu) {
    __shared__ float us[1024];
    const int b = blockIdx.y;
    const int e = blockIdx.x * 256 + threadIdx.x;
    for (int i = threadIdx.x; i < 1024; i += 256)
        us[i] = x[(size_t)b * 513 * 1024 + i];
    __syncthreads();
    const float* wu = w + (size_t)1024 * 1024;
    float acc = 0.f;
#pragma unroll 8
    for (int d = 0; d < 1024; ++d)
        acc = fmaf(us[d], wu[(size_t)d * 1024 + e], acc);
    hu[b * 1024 + e] = acc;
}

// ---------------------------------------------------------------------------
// Kernel 3: fused-conversion fp16 GEMM. BM=BN=256, BK=64, 512 thr / 8 waves
// (2Mx4N), wave = 128x64, acc[8][4]. Per K-step:
//   B: 4 global_load_lds(16B)/thread, pre-swizzled source;
//   A: 8 float4 loads from x (fp32), cvt to fp16, 4 swizzled ds_write_b128;
//   barrier; 2 k-subtiles x {12 ds_read_b128, 32 MFMA}; barrier.
// Swizzle (both sides): logical chunk c of row r at phys chunk c^(r&7).
__global__ __launch_bounds__(512, 2) void k_gemm10(
        const float* __restrict__ x,
        const _Float16* __restrict__ wzt,
        const float* __restrict__ hu,
        const float* __restrict__ bias,
        float* __restrict__ qp) {
    __shared__ __align__(16) _Float16 As[256 * 64];   // 32 KiB
    __shared__ __align__(16) _Float16 Bs[256 * 64];   // 32 KiB
    __shared__ float qred[2][4][128];                 // 4 KiB

    const int t = threadIdx.x;          // 0..511
    const int mtile = blockIdx.x;       // 0..127 (256 rows)
    const int ntile = blockIdx.y;       // 0..3   (256 cols)
    const int wid = t >> 6;
    const int l = t & 63;
    const int wm = wid >> 2;            // 0..1 -> rows wm*128
    const int wn = wid & 3;             // 0..3 -> cols wn*64
    const int lr = l & 15;
    const int g = l >> 4;               // 0..3

    // ---- staging maps (thread t, iteration j=0..3; row = (t>>3) + j*64) ----
    const int srow = t >> 3;                       // 0..63
    const int sphys = (t & 7) ^ (srow & 7);        // phys chunk for A write
    const int schunk = sphys;                      // B: src chunk = phys^(row&7)
    const int bb = mtile >> 1;                     // batch, block-uniform
    // A source rows in x (fp32): m = mtile*256 + row
    size_t aSrc[4];
#pragma unroll
    for (int j = 0; j < 4; ++j) {
        int m = mtile * 256 + srow + j * 64;
        int kk = m & 511;
        aSrc[j] = ((size_t)(bb * 513 + 1 + kk) << 10) + (t & 7) * 8;
    }
    // A LDS dest (bytes): row*128 + phys*16
    int aDst[4];
#pragma unroll
    for (int j = 0; j < 4; ++j)
        aDst[j] = (srow + j * 64) * 128 + sphys * 16;
    // B source (pre-swizzled chunk) and dest
    size_t bSrc[4];
#pragma unroll
    for (int j = 0; j < 4; ++j)
        bSrc[j] = (size_t)(ntile * 256 + srow + j * 64) * 1024 + schunk * 8;
    const int bDst0 = t * 16;                      // + j*8192

    f32x4 acc[8][4] = {};

    for (int k0 = 0; k0 < 1024; k0 += 64) {
        // ---- B: issue 4 direct global->LDS loads ----
#pragma unroll
        for (int j = 0; j < 4; ++j) {
            __builtin_amdgcn_global_load_lds(
                (gvoid_t*)(wzt + bSrc[j] + k0),
                (lvoid_t*)((char*)Bs + j * 8192 + bDst0), 16, 0, 0);
        }
        // ---- A: load fp32, convert, swizzled LDS write ----
#pragma unroll
        for (int j = 0; j < 4; ++j) {
            const float4 v0 = *(const float4*)(x + aSrc[j] + k0);
            const float4 v1 = *(const float4*)(x + aSrc[j] + k0 + 4);
            half8 hv;
            hv[0] = (_Float16)v0.x; hv[1] = (_Float16)v0.y;
            hv[2] = (_Float16)v0.z; hv[3] = (_Float16)v0.w;
            hv[4] = (_Float16)v1.x; hv[5] = (_Float16)v1.y;
            hv[6] = (_Float16)v1.z; hv[7] = (_Float16)v1.w;
            *(half8*)((char*)As + aDst[j]) = hv;
        }
        __syncthreads();   // drains vmcnt (B DMA) + lgkmcnt (A writes)

        // ---- compute: 2 k-subtiles of 32, 32 MFMA each ----
#pragma unroll
        for (int ks = 0; ks < 2; ++ks) {
            half8 afr[8], bfr[4];
            const int so = ((ks * 4 + g) ^ (lr & 7)) * 16;
#pragma unroll
            for (int ni = 0; ni < 4; ++ni)
                bfr[ni] = *(const half8*)((const char*)Bs + (wn * 64 + ni * 16 + lr) * 128 + so);
#pragma unroll
            for (int mi = 0; mi < 8; ++mi)
                afr[mi] = *(const half8*)((const char*)As + (wm * 128 + mi * 16 + lr) * 128 + so);
#pragma unroll
            for (int mi = 0; mi < 8; ++mi)
#pragma unroll
                for (int ni = 0; ni < 4; ++ni)
                    acc[mi][ni] = __builtin_amdgcn_mfma_f32_16x16x32_f16(
                        afr[mi], bfr[ni], acc[mi][ni], 0, 0, 0);
        }
        __syncthreads();
    }

    // ---- epilogue: partial q over this wave's 64 e-cols ----
    float hu4[4], bias4[4];
#pragma unroll
    for (int ni = 0; ni < 4; ++ni) {
        int e = ntile * 256 + wn * 64 + ni * 16 + lr;
        hu4[ni] = hu[bb * 1024 + e];
        bias4[ni] = bias[e];
    }
#pragma unroll
    for (int mi = 0; mi < 8; ++mi) {
#pragma unroll
        for (int j = 0; j < 4; ++j) {
            float v = 0.f;
#pragma unroll
            for (int ni = 0; ni < 4; ++ni)
                v += tanh_fast(acc[mi][ni][j] + hu4[ni]) * bias4[ni];
            v += __shfl_xor(v, 1);
            v += __shfl_xor(v, 2);
            v += __shfl_xor(v, 4);
            v += __shfl_xor(v, 8);
            if (lr == 0)
                qred[wm][wn][mi * 16 + g * 4 + j] = v;
        }
    }
    __syncthreads();
    if (t < 256) {
        const int wmr = t >> 7;
        const int rr = t & 127;
        float q = qred[wmr][0][rr] + qred[wmr][1][rr]
                + qred[wmr][2][rr] + qred[wmr][3][rr];
        qp[(size_t)ntile * 32768 + mtile * 256 + t] = q;
    }
}

// ---------------------------------------------------------------------------
// Fallback path (R2-verified): split-bf16, in-loop staging (ws too small).
__global__ void k_prep_w(const float* __restrict__ w,
                         ushort_t* __restrict__ wzt_hi,
                         ushort_t* __restrict__ wzt_lo) {
    __shared__ ushort_t th[64][66];
    __shared__ ushort_t tl[64][66];
    const int k0 = blockIdx.x * 64;
    const int n0 = blockIdx.y * 64;
    const int t = threadIdx.x;
    const int lr = t >> 6;
    const int lc = t & 63;
#pragma unroll
    for (int r = 0; r < 16; ++r) {
        int kk = r * 4 + lr;
        float f = w[(size_t)(k0 + kk) * 1024 + n0 + lc];
        ushort_t hi = f2bf(f);
        ushort_t lo = f2bf(f - bf2f(hi));
        th[kk][lc] = hi;
        tl[kk][lc] = lo;
    }
    __syncthreads();
#pragma unroll
    for (int r = 0; r < 16; ++r) {
        int nn = r * 4 + lr;
        wzt_hi[(size_t)(n0 + nn) * 1024 + k0 + lc] = th[lc][nn];
        wzt_lo[(size_t)(n0 + nn) * 1024 + k0 + lc] = tl[lc][nn];
    }
}

__global__ __launch_bounds__(256) void k_gemm(
        const float* __restrict__ x,
        const ushort_t* __restrict__ wzt_hi,
        const ushort_t* __restrict__ wzt_lo,
        const float* __restrict__ hu,
        const float* __restrict__ bias,
        float* __restrict__ qp) {
    __shared__ ushort_t As_hi[128][40];
    __shared__ ushort_t As_lo[128][40];
    __shared__ ushort_t Bs_hi[128][40];
    __shared__ ushort_t Bs_lo[128][40];
    __shared__ float qred[2][2][64];

    const int t = threadIdx.x;
    const int mtile = blockIdx.x;
    const int ntile = blockIdx.y;
    const int wid = t >> 6;
    const int l = t & 63;
    const int wm = wid >> 1;
    const int wn = wid & 1;

    f32x4 acc[4][4] = {};

    const int arow = t >> 3;
    const int acol = (t & 7) * 4;
    size_t abase[4];
#pragma unroll
    for (int it = 0; it < 4; ++it) {
        int m = mtile * 128 + arow + it * 32;
        int bb = m >> 9;
        int kk = m & 511;
        abase[it] = ((size_t)(bb * 513 + 1 + kk)) * 1024 + acol;
    }
    const int brow = t >> 2;
    const int bcol = (t & 3) * 8;
    const size_t bbase = (size_t)(ntile * 128 + brow) * 1024 + bcol;

    for (int k0 = 0; k0 < 1024; k0 += 32) {
#pragma unroll
        for (int it = 0; it < 4; ++it) {
            const float4 v = *(const float4*)(x + abase[it] + k0);
            ushort4 hv, lv;
            hv.x = f2bf(v.x); lv.x = f2bf(v.x - bf2f(hv.x));
            hv.y = f2bf(v.y); lv.y = f2bf(v.y - bf2f(hv.y));
            hv.z = f2bf(v.z); lv.z = f2bf(v.z - bf2f(hv.z));
            hv.w = f2bf(v.w); lv.w = f2bf(v.w - bf2f(hv.w));
            const int row = arow + it * 32;
            *(ushort4*)&As_hi[row][acol] = hv;
            *(ushort4*)&As_lo[row][acol] = lv;
        }
#pragma unroll
        for (int it = 0; it < 2; ++it) {
            const int row = brow + it * 64;
            const uint4 vh = *(const uint4*)(wzt_hi + bbase + (size_t)it * 64 * 1024 + k0);
            const uint4 vl = *(const uint4*)(wzt_lo + bbase + (size_t)it * 64 * 1024 + k0);
            *(uint4*)&Bs_hi[row][bcol] = vh;
            *(uint4*)&Bs_lo[row][bcol] = vl;
        }
        __syncthreads();

        const int lr = l & 15;
        const int lk = (l >> 4) * 8;
        short8 ah[4], al[4], bh[4], bl[4];
#pragma unroll
        for (int i = 0; i < 4; ++i) {
            ah[i] = *(const short8*)&As_hi[wm * 64 + i * 16 + lr][lk];
            al[i] = *(const short8*)&As_lo[wm * 64 + i * 16 + lr][lk];
            bh[i] = *(const short8*)&Bs_hi[wn * 64 + i * 16 + lr][lk];
            bl[i] = *(const short8*)&Bs_lo[wn * 64 + i * 16 + lr][lk];
        }
#pragma unroll
        for (int mi = 0; mi < 4; ++mi)
#pragma unroll
            for (int ni = 0; ni < 4; ++ni) {
                acc[mi][ni] = __builtin_amdgcn_mfma_f32_16x16x32_bf16(ah[mi], bh[ni], acc[mi][ni], 0, 0, 0);
                acc[mi][ni] = __builtin_amdgcn_mfma_f32_16x16x32_bf16(ah[mi], bl[ni], acc[mi][ni], 0, 0, 0);
                acc[mi][ni] = __builtin_amdgcn_mfma_f32_16x16x32_bf16(al[mi], bh[ni], acc[mi][ni], 0, 0, 0);
            }
        __syncthreads();
    }

    const int lr = l & 15;
    const int lg = l >> 4;
    const int bbatch = mtile >> 2;
    float hu4[4], bias4[4];
#pragma unroll
    for (int ni = 0; ni < 4; ++ni) {
        int e = ntile * 128 + wn * 64 + ni * 16 + lr;
        hu4[ni] = hu[bbatch * 1024 + e];
        bias4[ni] = bias[e];
    }
#pragma unroll
    for (int mi = 0; mi < 4; ++mi) {
#pragma unroll
        for (int j = 0; j < 4; ++j) {
            float v = 0.f;
#pragma unroll
            for (int ni = 0; ni < 4; ++ni)
                v += tanhf(acc[mi][ni][j] + hu4[ni]) * bias4[ni];
            v += __shfl_xor(v, 1);
            v += __shfl_xor(v, 2);
            v += __shfl_xor(v, 4);
            v += __shfl_xor(v, 8);
            if (lr == 0)
                qred[wm][wn][mi * 16 + lg * 4 + j] = v;
        }
    }
    __syncthreads();
    if (t < 128) {
        const int wmr = t >> 6;
        const int rr = t & 63;
        float qv = qred[wmr][0][rr] + qred[wmr][1][rr];
        qp[(size_t)ntile * 32768 + mtile * 128 + t] = qv;
    }
}

// ---------------------------------------------------------------------------
// Kernel 4: reduce partials over nt tiles + softmax over k (512) per batch.
__global__ void k_softmax(const float* __restrict__ qp, float* __restrict__ out,
                          int nt) {
    const int b = blockIdx.x;
    const int k = threadIdx.x;   // 512 threads
    float q = 0.f;
    for (int i = 0; i < nt; ++i)
        q += qp[(size_t)i * 32768 + b * 512 + k];

    __shared__ float redm[8];
    __shared__ float reds[8];
    const int wid = k >> 6;

    float m = q;
#pragma unroll
    for (int off = 32; off >= 1; off >>= 1)
        m = fmaxf(m, __shfl_xor(m, off));
    if ((k & 63) == 0) redm[wid] = m;
    __syncthreads();
    m = redm[0];
#pragma unroll
    for (int i = 1; i < 8; ++i) m = fmaxf(m, redm[i]);

    float p = expf(q - m);
    float s = p;
#pragma unroll
    for (int off = 32; off >= 1; off >>= 1)
        s += __shfl_xor(s, off);
    if ((k & 63) == 0) reds[wid] = s;
    __syncthreads();
    s = 0.f;
#pragma unroll
    for (int i = 0; i < 8; ++i) s += reds[i];

    out[b * 512 + k] = p / s;
}

// ---------------------------------------------------------------------------
extern "C" void kernel_launch(void* const* d_in, const int* in_sizes, int n_in,
                              void* d_out, int out_size, void* d_ws, size_t ws_size,
                              hipStream_t stream) {
    const float* x    = (const float*)d_in[0];   // (64, 513, 1024) f32
    const float* w    = (const float*)d_in[1];   // (2048, 1024) f32
    const float* bias = (const float*)d_in[2];   // (1024, 1) f32
    float* out = (float*)d_out;                  // (64, 512) f32

    char* ws = (char*)d_ws;

    // fast-path ws: wzt (2MB fp16) + hu (256KB) + qp (512KB)
    const size_t need = (size_t)1024 * 1024 * sizeof(_Float16)
                      + (size_t)64 * 1024 * sizeof(float)
                      + (size_t)4 * 32768 * sizeof(float);

    if (ws_size >= need) {
        _Float16* wzt = (_Float16*)ws;
        float*    hu  = (float*)(wzt + (size_t)1024 * 1024);
        float*    qp  = hu + (size_t)64 * 1024;

        k_prep_w16<<<dim3(16, 16), 256, 0, stream>>>(w, wzt);
        k_hu<<<dim3(4, 64), 256, 0, stream>>>(x, w, hu);
        k_gemm10<<<dim3(128, 4), 512, 0, stream>>>(x, wzt, hu, bias, qp);
        k_softmax<<<64, 512, 0, stream>>>(qp, out, 4);
    } else {
        ushort_t* wzt_hi = (ushort_t*)ws;
        ushort_t* wzt_lo = wzt_hi + (size_t)1024 * 1024;
        float* hu = (float*)(ws + (size_t)4 * 1024 * 1024);
        float* qp = hu + (size_t)64 * 1024;

        k_prep_w<<<dim3(16, 16), 256, 0, stream>>>(w, wzt_hi, wzt_lo);
        k_hu<<<dim3(4, 64), 256, 0, stream>>>(x, w, hu);
        k_gemm<<<dim3(256, 8), 256, 0, stream>>>(x, wzt_hi, wzt_lo, hu, bias, qp);
        k_softmax<<<64, 512, 0, stream>>>(qp, out, 8);
    }
}

// Round 12
// 173.262 us; speedup vs baseline: 1.6869x; 1.0051x over previous
//
#include <hip/hip_runtime.h>
#include <hip/hip_bf16.h>

// Problem: B=64, K=512 (KPLUS1=513), D=E=1024
// out[b,k] = softmax_k( sum_e tanh( (z[b,k,:]@Wz)[e] + (u[b,:]@Wu)[e] ) * bias[e] )
// R12: fused-conversion fp16 GEMM with a 2-phase double-buffered pipeline:
// prefetch A(T+1)->regs and B(T+1)->LDS-DMA while computing T; counted
// vmcnt(12) (never 0 mid-loop); raw s_barrier. BM=BN=256, BK=64, 8 waves.
// Maps/swizzle/epilogue identical to R11's verified k_gemm10.

typedef __attribute__((ext_vector_type(8))) short short8;
typedef __attribute__((ext_vector_type(8))) _Float16 half8;
typedef __attribute__((ext_vector_type(4))) float f32x4;
typedef unsigned short ushort_t;

typedef const __attribute__((address_space(1))) void gvoid_t;
typedef __attribute__((address_space(3))) void lvoid_t;

__device__ __forceinline__ ushort_t f2bf(float f) {
    unsigned u = __float_as_uint(f);
    unsigned r = u + 0x7FFFu + ((u >> 16) & 1u);
    return (ushort_t)(r >> 16);
}
__device__ __forceinline__ float bf2f(ushort_t h) {
    return __uint_as_float(((unsigned)h) << 16);
}
__device__ __forceinline__ float tanh_fast(float x) {
    float e = __expf(2.f * x);
    return 1.f - 2.f / (e + 1.f);
}

// ---------------------------------------------------------------------------
// Kernel 1: transpose Wz ([d][e], rows 0..1023 of dense_weights) -> fp16 [e][d].
__global__ void k_prep_w16(const float* __restrict__ w,
                           _Float16* __restrict__ wzt) {
    __shared__ _Float16 th[64][66];
    const int k0 = blockIdx.x * 64;
    const int n0 = blockIdx.y * 64;
    const int t = threadIdx.x;
    const int lr = t >> 6;
    const int lc = t & 63;
#pragma unroll
    for (int r = 0; r < 16; ++r) {
        int kk = r * 4 + lr;
        th[kk][lc] = (_Float16)w[(size_t)(k0 + kk) * 1024 + n0 + lc];
    }
    __syncthreads();
#pragma unroll
    for (int r = 0; r < 16; ++r) {
        int nn = r * 4 + lr;
        wzt[(size_t)(n0 + nn) * 1024 + k0 + lc] = th[lc][nn];
    }
}

// ---------------------------------------------------------------------------
// Kernel 2: hu[b][e] = sum_d u[b][d] * Wu[d][e], exact fp32.
__global__ void k_hu(const float* __restrict__ x,
                     const float* __restrict__ w,
                     float* __restrict__ hu) {
    __shared__ float us[1024];
    const int b = blockIdx.y;
    const int e = blockIdx.x * 256 + threadIdx.x;
    for (int i = threadIdx.x; i < 1024; i += 256)
        us[i] = x[(size_t)b * 513 * 1024 + i];
    __syncthreads();
    const float* wu = w + (size_t)1024 * 1024;
    float acc = 0.f;
#pragma unroll 8
    for (int d = 0; d < 1024; ++d)
        acc = fmaf(us[d], wu[(size_t)d * 1024 + e], acc);
    hu[b * 1024 + e] = acc;
}

// ---------------------------------------------------------------------------
// Kernel 3: pipelined fused-conversion fp16 GEMM.
// LDS: 2 buffers x [A 32KB | B 32KB]; buf = T&1.
// Per iter: cvt+ds_write A(T); issue A(T+1) 8xglobal_load + B(T+1)
// 4xglobal_load_lds; lgkmcnt(0); vmcnt(12); s_barrier; 64 MFMA; s_barrier.
__global__ __launch_bounds__(512, 2) void k_gemm11(
        const float* __restrict__ x,
        const _Float16* __restrict__ wzt,
        const float* __restrict__ hu,
        const float* __restrict__ bias,
        float* __restrict__ qp) {
    __shared__ __align__(16) char lds[2 * 65536];     // 128 KiB
    __shared__ float qred[2][4][128];                 // 4 KiB

    const int t = threadIdx.x;          // 0..511
    const int mtile = blockIdx.x;       // 0..127 (256 rows)
    const int ntile = blockIdx.y;       // 0..3   (256 cols)
    const int wid = t >> 6;
    const int l = t & 63;
    const int wm = wid >> 2;            // 0..1 -> rows wm*128
    const int wn = wid & 3;             // 0..3 -> cols wn*64
    const int lr = l & 15;
    const int g = l >> 4;               // 0..3

    // ---- staging maps (R11-verified): j=0..3, row = (t>>3)+j*64 ----
    const int srow = t >> 3;                       // 0..63
    const int sphys = (t & 7) ^ (srow & 7);        // phys chunk (both A and B)
    const int bb = mtile >> 1;                     // batch, block-uniform
    size_t aSrc[4];
    int aDst[4];
    size_t bSrc[4];
#pragma unroll
    for (int j = 0; j < 4; ++j) {
        int m = mtile * 256 + srow + j * 64;
        int kk = m & 511;
        aSrc[j] = ((size_t)(bb * 513 + 1 + kk) << 10) + (t & 7) * 8;
        aDst[j] = (srow + j * 64) * 128 + sphys * 16;
        bSrc[j] = (size_t)(ntile * 256 + srow + j * 64) * 1024 + sphys * 8;
    }
    const int bDst0 = 32768 + t * 16;              // B region, + j*8192

    f32x4 acc[8][4] = {};
    float4 pa0_, pa1_, pa2_, pa3_, pb0_, pb1_, pb2_, pb3_;  // A prefetch regs

#define A_LOAD(k0)                                                           \
    {   pa0_ = *(const float4*)(x + aSrc[0] + (k0));                         \
        pb0_ = *(const float4*)(x + aSrc[0] + (k0) + 4);                     \
        pa1_ = *(const float4*)(x + aSrc[1] + (k0));                         \
        pb1_ = *(const float4*)(x + aSrc[1] + (k0) + 4);                     \
        pa2_ = *(const float4*)(x + aSrc[2] + (k0));                         \
        pb2_ = *(const float4*)(x + aSrc[2] + (k0) + 4);                     \
        pa3_ = *(const float4*)(x + aSrc[3] + (k0));                         \
        pb3_ = *(const float4*)(x + aSrc[3] + (k0) + 4); }

#define B_STAGE(k0, BUF)                                                     \
    {   _Pragma("unroll")                                                    \
        for (int j = 0; j < 4; ++j)                                          \
            __builtin_amdgcn_global_load_lds(                                \
                (gvoid_t*)(wzt + bSrc[j] + (k0)),                            \
                (lvoid_t*)((BUF) + bDst0 + j * 8192), 16, 0, 0); }

#define A_CVT_WRITE(BUF)                                                     \
    {   half8 hv;                                                            \
        hv[0] = (_Float16)pa0_.x; hv[1] = (_Float16)pa0_.y;                  \
        hv[2] = (_Float16)pa0_.z; hv[3] = (_Float16)pa0_.w;                  \
        hv[4] = (_Float16)pb0_.x; hv[5] = (_Float16)pb0_.y;                  \
        hv[6] = (_Float16)pb0_.z; hv[7] = (_Float16)pb0_.w;                  \
        *(half8*)((BUF) + aDst[0]) = hv;                                     \
        hv[0] = (_Float16)pa1_.x; hv[1] = (_Float16)pa1_.y;                  \
        hv[2] = (_Float16)pa1_.z; hv[3] = (_Float16)pa1_.w;                  \
        hv[4] = (_Float16)pb1_.x; hv[5] = (_Float16)pb1_.y;                  \
        hv[6] = (_Float16)pb1_.z; hv[7] = (_Float16)pb1_.w;                  \
        *(half8*)((BUF) + aDst[1]) = hv;                                     \
        hv[0] = (_Float16)pa2_.x; hv[1] = (_Float16)pa2_.y;                  \
        hv[2] = (_Float16)pa2_.z; hv[3] = (_Float16)pa2_.w;                  \
        hv[4] = (_Float16)pb2_.x; hv[5] = (_Float16)pb2_.y;                  \
        hv[6] = (_Float16)pb2_.z; hv[7] = (_Float16)pb2_.w;                  \
        *(half8*)((BUF) + aDst[2]) = hv;                                     \
        hv[0] = (_Float16)pa3_.x; hv[1] = (_Float16)pa3_.y;                  \
        hv[2] = (_Float16)pa3_.z; hv[3] = (_Float16)pa3_.w;                  \
        hv[4] = (_Float16)pb3_.x; hv[5] = (_Float16)pb3_.y;                  \
        hv[6] = (_Float16)pb3_.z; hv[7] = (_Float16)pb3_.w;                  \
        *(half8*)((BUF) + aDst[3]) = hv; }

#define COMPUTE(BUF)                                                         \
    {   _Pragma("unroll")                                                    \
        for (int ks = 0; ks < 2; ++ks) {                                     \
            half8 afr[8], bfr[4];                                            \
            const int so = ((ks * 4 + g) ^ (lr & 7)) * 16;                   \
            _Pragma("unroll")                                                \
            for (int ni = 0; ni < 4; ++ni)                                   \
                bfr[ni] = *(const half8*)((BUF) + 32768                      \
                          + (wn * 64 + ni * 16 + lr) * 128 + so);            \
            _Pragma("unroll")                                                \
            for (int mi = 0; mi < 8; ++mi)                                   \
                afr[mi] = *(const half8*)((BUF)                              \
                          + (wm * 128 + mi * 16 + lr) * 128 + so);           \
            __builtin_amdgcn_s_setprio(1);                                   \
            _Pragma("unroll")                                                \
            for (int mi = 0; mi < 8; ++mi)                                   \
                _Pragma("unroll")                                            \
                for (int ni = 0; ni < 4; ++ni)                               \
                    acc[mi][ni] = __builtin_amdgcn_mfma_f32_16x16x32_f16(    \
                        afr[mi], bfr[ni], acc[mi][ni], 0, 0, 0);             \
            __builtin_amdgcn_s_setprio(0);                                   \
        } }

    // ---- prologue: A(0) -> regs, B(0) -> buf0 ----
    A_LOAD(0)
    B_STAGE(0, lds)

    // ---- main loop: T = 0..14 with prefetch of T+1 ----
#pragma unroll 1
    for (int T = 0; T < 15; ++T) {
        char* buf = lds + (T & 1) * 65536;
        char* nbuf = lds + ((T + 1) & 1) * 65536;
        const int k1 = (T + 1) * 64;
        A_CVT_WRITE(buf)                 // compiler waits A(T) regs: vmcnt(4)
        A_LOAD(k1)                       // 8 loads -> regs
        B_STAGE(k1, nbuf)                // 4 DMA -> other buffer
        asm volatile("s_waitcnt lgkmcnt(0)" ::: "memory");   // A writes done
        asm volatile("s_waitcnt vmcnt(12)" ::: "memory");    // B(T) landed
        __builtin_amdgcn_sched_barrier(0);
        __builtin_amdgcn_s_barrier();
        COMPUTE(buf)
        __builtin_amdgcn_s_barrier();
        __builtin_amdgcn_sched_barrier(0);
    }
    // ---- final iteration T=15 (no prefetch) ----
    {
        char* buf = lds + (15 & 1) * 65536;
        A_CVT_WRITE(buf)
        asm volatile("s_waitcnt lgkmcnt(0)" ::: "memory");
        asm volatile("s_waitcnt vmcnt(0)" ::: "memory");
        __builtin_amdgcn_sched_barrier(0);
        __builtin_amdgcn_s_barrier();
        COMPUTE(buf)
        __builtin_amdgcn_s_barrier();
    }
#undef COMPUTE
#undef A_CVT_WRITE
#undef B_STAGE
#undef A_LOAD

    // ---- epilogue: partial q over this wave's 64 e-cols (R11-verified) ----
    float hu4[4], bias4[4];
#pragma unroll
    for (int ni = 0; ni < 4; ++ni) {
        int e = ntile * 256 + wn * 64 + ni * 16 + lr;
        hu4[ni] = hu[bb * 1024 + e];
        bias4[ni] = bias[e];
    }
#pragma unroll
    for (int mi = 0; mi < 8; ++mi) {
#pragma unroll
        for (int j = 0; j < 4; ++j) {
            float v = 0.f;
#pragma unroll
            for (int ni = 0; ni < 4; ++ni)
                v += tanh_fast(acc[mi][ni][j] + hu4[ni]) * bias4[ni];
            v += __shfl_xor(v, 1);
            v += __shfl_xor(v, 2);
            v += __shfl_xor(v, 4);
            v += __shfl_xor(v, 8);
            if (lr == 0)
                qred[wm][wn][mi * 16 + g * 4 + j] = v;
        }
    }
    __syncthreads();
    if (t < 256) {
        const int wmr = t >> 7;
        const int rr = t & 127;
        float q = qred[wmr][0][rr] + qred[wmr][1][rr]
                + qred[wmr][2][rr] + qred[wmr][3][rr];
        qp[(size_t)ntile * 32768 + mtile * 256 + t] = q;
    }
}

// ---------------------------------------------------------------------------
// Fallback path (R2-verified): split-bf16, in-loop staging (ws too small).
__global__ void k_prep_w(const float* __restrict__ w,
                         ushort_t* __restrict__ wzt_hi,
                         ushort_t* __restrict__ wzt_lo) {
    __shared__ ushort_t th[64][66];
    __shared__ ushort_t tl[64][66];
    const int k0 = blockIdx.x * 64;
    const int n0 = blockIdx.y * 64;
    const int t = threadIdx.x;
    const int lr = t >> 6;
    const int lc = t & 63;
#pragma unroll
    for (int r = 0; r < 16; ++r) {
        int kk = r * 4 + lr;
        float f = w[(size_t)(k0 + kk) * 1024 + n0 + lc];
        ushort_t hi = f2bf(f);
        ushort_t lo = f2bf(f - bf2f(hi));
        th[kk][lc] = hi;
        tl[kk][lc] = lo;
    }
    __syncthreads();
#pragma unroll
    for (int r = 0; r < 16; ++r) {
        int nn = r * 4 + lr;
        wzt_hi[(size_t)(n0 + nn) * 1024 + k0 + lc] = th[lc][nn];
        wzt_lo[(size_t)(n0 + nn) * 1024 + k0 + lc] = tl[lc][nn];
    }
}

__global__ __launch_bounds__(256) void k_gemm(
        const float* __restrict__ x,
        const ushort_t* __restrict__ wzt_hi,
        const ushort_t* __restrict__ wzt_lo,
        const float* __restrict__ hu,
        const float* __restrict__ bias,
        float* __restrict__ qp) {
    __shared__ ushort_t As_hi[128][40];
    __shared__ ushort_t As_lo[128][40];
    __shared__ ushort_t Bs_hi[128][40];
    __shared__ ushort_t Bs_lo[128][40];
    __shared__ float qred[2][2][64];

    const int t = threadIdx.x;
    const int mtile = blockIdx.x;
    const int ntile = blockIdx.y;
    const int wid = t >> 6;
    const int l = t & 63;
    const int wm = wid >> 1;
    const int wn = wid & 1;

    f32x4 acc[4][4] = {};

    const int arow = t >> 3;
    const int acol = (t & 7) * 4;
    size_t abase[4];
#pragma unroll
    for (int it = 0; it < 4; ++it) {
        int m = mtile * 128 + arow + it * 32;
        int bb = m >> 9;
        int kk = m & 511;
        abase[it] = ((size_t)(bb * 513 + 1 + kk)) * 1024 + acol;
    }
    const int brow = t >> 2;
    const int bcol = (t & 3) * 8;
    const size_t bbase = (size_t)(ntile * 128 + brow) * 1024 + bcol;

    for (int k0 = 0; k0 < 1024; k0 += 32) {
#pragma unroll
        for (int it = 0; it < 4; ++it) {
            const float4 v = *(const float4*)(x + abase[it] + k0);
            ushort4 hv, lv;
            hv.x = f2bf(v.x); lv.x = f2bf(v.x - bf2f(hv.x));
            hv.y = f2bf(v.y); lv.y = f2bf(v.y - bf2f(hv.y));
            hv.z = f2bf(v.z); lv.z = f2bf(v.z - bf2f(hv.z));
            hv.w = f2bf(v.w); lv.w = f2bf(v.w - bf2f(hv.w));
            const int row = arow + it * 32;
            *(ushort4*)&As_hi[row][acol] = hv;
            *(ushort4*)&As_lo[row][acol] = lv;
        }
#pragma unroll
        for (int it = 0; it < 2; ++it) {
            const int row = brow + it * 64;
            const uint4 vh = *(const uint4*)(wzt_hi + bbase + (size_t)it * 64 * 1024 + k0);
            const uint4 vl = *(const uint4*)(wzt_lo + bbase + (size_t)it * 64 * 1024 + k0);
            *(uint4*)&Bs_hi[row][bcol] = vh;
            *(uint4*)&Bs_lo[row][bcol] = vl;
        }
        __syncthreads();

        const int lr = l & 15;
        const int lk = (l >> 4) * 8;
        short8 ah[4], al[4], bh[4], bl[4];
#pragma unroll
        for (int i = 0; i < 4; ++i) {
            ah[i] = *(const short8*)&As_hi[wm * 64 + i * 16 + lr][lk];
            al[i] = *(const short8*)&As_lo[wm * 64 + i * 16 + lr][lk];
            bh[i] = *(const short8*)&Bs_hi[wn * 64 + i * 16 + lr][lk];
            bl[i] = *(const short8*)&Bs_lo[wn * 64 + i * 16 + lr][lk];
        }
#pragma unroll
        for (int mi = 0; mi < 4; ++mi)
#pragma unroll
            for (int ni = 0; ni < 4; ++ni) {
                acc[mi][ni] = __builtin_amdgcn_mfma_f32_16x16x32_bf16(ah[mi], bh[ni], acc[mi][ni], 0, 0, 0);
                acc[mi][ni] = __builtin_amdgcn_mfma_f32_16x16x32_bf16(ah[mi], bl[ni], acc[mi][ni], 0, 0, 0);
                acc[mi][ni] = __builtin_amdgcn_mfma_f32_16x16x32_bf16(al[mi], bh[ni], acc[mi][ni], 0, 0, 0);
            }
        __syncthreads();
    }

    const int lr = l & 15;
    const int lg = l >> 4;
    const int bbatch = mtile >> 2;
    float hu4[4], bias4[4];
#pragma unroll
    for (int ni = 0; ni < 4; ++ni) {
        int e = ntile * 128 + wn * 64 + ni * 16 + lr;
        hu4[ni] = hu[bbatch * 1024 + e];
        bias4[ni] = bias[e];
    }
#pragma unroll
    for (int mi = 0; mi < 4; ++mi) {
#pragma unroll
        for (int j = 0; j < 4; ++j) {
            float v = 0.f;
#pragma unroll
            for (int ni = 0; ni < 4; ++ni)
                v += tanhf(acc[mi][ni][j] + hu4[ni]) * bias4[ni];
            v += __shfl_xor(v, 1);
            v += __shfl_xor(v, 2);
            v += __shfl_xor(v, 4);
            v += __shfl_xor(v, 8);
            if (lr == 0)
                qred[wm][wn][mi * 16 + lg * 4 + j] = v;
        }
    }
    __syncthreads();
    if (t < 128) {
        const int wmr = t >> 6;
        const int rr = t & 63;
        float qv = qred[wmr][0][rr] + qred[wmr][1][rr];
        qp[(size_t)ntile * 32768 + mtile * 128 + t] = qv;
    }
}

// ---------------------------------------------------------------------------
// Kernel 4: reduce partials over nt tiles + softmax over k (512) per batch.
__global__ void k_softmax(const float* __restrict__ qp, float* __restrict__ out,
                          int nt) {
    const int b = blockIdx.x;
    const int k = threadIdx.x;   // 512 threads
    float q = 0.f;
    for (int i = 0; i < nt; ++i)
        q += qp[(size_t)i * 32768 + b * 512 + k];

    __shared__ float redm[8];
    __shared__ float reds[8];
    const int wid = k >> 6;

    float m = q;
#pragma unroll
    for (int off = 32; off >= 1; off >>= 1)
        m = fmaxf(m, __shfl_xor(m, off));
    if ((k & 63) == 0) redm[wid] = m;
    __syncthreads();
    m = redm[0];
#pragma unroll
    for (int i = 1; i < 8; ++i) m = fmaxf(m, redm[i]);

    float p = expf(q - m);
    float s = p;
#pragma unroll
    for (int off = 32; off >= 1; off >>= 1)
        s += __shfl_xor(s, off);
    if ((k & 63) == 0) reds[wid] = s;
    __syncthreads();
    s = 0.f;
#pragma unroll
    for (int i = 0; i < 8; ++i) s += reds[i];

    out[b * 512 + k] = p / s;
}

// ---------------------------------------------------------------------------
extern "C" void kernel_launch(void* const* d_in, const int* in_sizes, int n_in,
                              void* d_out, int out_size, void* d_ws, size_t ws_size,
                              hipStream_t stream) {
    const float* x    = (const float*)d_in[0];   // (64, 513, 1024) f32
    const float* w    = (const float*)d_in[1];   // (2048, 1024) f32
    const float* bias = (const float*)d_in[2];   // (1024, 1) f32
    float* out = (float*)d_out;                  // (64, 512) f32

    char* ws = (char*)d_ws;

    // fast-path ws: wzt (2MB fp16) + hu (256KB) + qp (512KB)
    const size_t need = (size_t)1024 * 1024 * sizeof(_Float16)
                      + (size_t)64 * 1024 * sizeof(float)
                      + (size_t)4 * 32768 * sizeof(float);

    if (ws_size >= need) {
        _Float16* wzt = (_Float16*)ws;
        float*    hu  = (float*)(wzt + (size_t)1024 * 1024);
        float*    qp  = hu + (size_t)64 * 1024;

        k_prep_w16<<<dim3(16, 16), 256, 0, stream>>>(w, wzt);
        k_hu<<<dim3(4, 64), 256, 0, stream>>>(x, w, hu);
        k_gemm11<<<dim3(128, 4), 512, 0, stream>>>(x, wzt, hu, bias, qp);
        k_softmax<<<64, 512, 0, stream>>>(qp, out, 4);
    } else {
        ushort_t* wzt_hi = (ushort_t*)ws;
        ushort_t* wzt_lo = wzt_hi + (size_t)1024 * 1024;
        float* hu = (float*)(ws + (size_t)4 * 1024 * 1024);
        float* qp = hu + (size_t)64 * 1024;

        k_prep_w<<<dim3(16, 16), 256, 0, stream>>>(w, wzt_hi, wzt_lo);
        k_hu<<<dim3(4, 64), 256, 0, stream>>>(x, w, hu);
        k_gemm<<<dim3(256, 8), 256, 0, stream>>>(x, wzt_hi, wzt_lo, hu, bias, qp);
        k_softmax<<<64, 512, 0, stream>>>(qp, out, 8);
    }
}